// Round 5
// baseline (250.670 us; speedup 1.0000x reference)
//
#include <hip/hip_runtime.h>

#define L_SEQ  2048
#define EMB    1024
#define NHEAD  16
#define HDIM   64
#define NBATCH 2

typedef unsigned short u16;
typedef unsigned long long u64;
typedef short bf16x8 __attribute__((ext_vector_type(8)));
typedef float f32x4  __attribute__((ext_vector_type(4)));

static __device__ __forceinline__ u16 f2bf(float x) {
    union { float f; unsigned u; } a; a.f = x;
    unsigned r = a.u + 0x7FFFu + ((a.u >> 16) & 1u);
    return (u16)(r >> 16);
}
static __device__ __forceinline__ void cvt8(const float4& a, const float4& b, u16* o, float s) {
    o[0]=f2bf(a.x*s); o[1]=f2bf(a.y*s); o[2]=f2bf(a.z*s); o[3]=f2bf(a.w*s);
    o[4]=f2bf(b.x*s); o[5]=f2bf(b.y*s); o[6]=f2bf(b.z*s); o[7]=f2bf(b.w*s);
}

#define QKV_BLOCKS  1024
#define WCVT_BLOCKS 512
// total prep grid = 1024 + 512 + 4096

// ---------------------------------------------------------------------------
// Fused prep: [0,1024) QKV convert (+V transpose, swizzled LDS);
// [1024,1536) W fp32->bf16; [1536,5632) mask bit-pack (4 waves x 8 tiles).
// ---------------------------------------------------------------------------
__global__ __launch_bounds__(256, 4)
void prep_all(const float* __restrict__ Qg, const float* __restrict__ Kg,
              const float* __restrict__ Vg, const float* __restrict__ Wg,
              const int* __restrict__ Mg, u16* __restrict__ Qb,
              u16* __restrict__ Kb, u16* __restrict__ Vt,
              u16* __restrict__ Wb, u64* __restrict__ maskp)
{
    const int b   = blockIdx.x;
    const int tid = threadIdx.x;

    __shared__ u16 Vl2[64][72];

    if (b < QKV_BLOCKS) {
        const int t = b & 31, h = (b >> 5) & 15, n = b >> 9;
        const int row = tid >> 2;            // k-row 0..63
        const int dc  = (tid & 3) * 16;      // d chunk base
        const size_t gin = ((size_t)(n * L_SEQ) + t * 64 + row) * EMB + h * HDIM + dc;

        // Q: scale + convert (layout preserved)
        {
            u16 o[16];
            cvt8(*(const float4*)(Qg + gin),     *(const float4*)(Qg + gin + 4),  o,     0.125f);
            cvt8(*(const float4*)(Qg + gin + 8), *(const float4*)(Qg + gin + 12), o + 8, 0.125f);
            *(uint4*)(Qb + gin)     = *(const uint4*)o;
            *(uint4*)(Qb + gin + 8) = *(const uint4*)&o[8];
        }
        // K: convert, head-major [n,h,k,d]
        {
            u16 o[16];
            cvt8(*(const float4*)(Kg + gin),     *(const float4*)(Kg + gin + 4),  o,     1.f);
            cvt8(*(const float4*)(Kg + gin + 8), *(const float4*)(Kg + gin + 12), o + 8, 1.f);
            size_t ko = ((size_t)(n * NHEAD + h) * L_SEQ + t * 64 + row) * HDIM + dc;
            *(uint4*)(Kb + ko)     = *(const uint4*)o;
            *(uint4*)(Kb + ko + 8) = *(const uint4*)&o[8];
        }
        // V: convert + transpose via swizzled LDS (conflict-free scatter)
        {
            u16 o[16];
            cvt8(*(const float4*)(Vg + gin),     *(const float4*)(Vg + gin + 4),  o,     1.f);
            cvt8(*(const float4*)(Vg + gin + 8), *(const float4*)(Vg + gin + 12), o + 8, 1.f);
            #pragma unroll
            for (int j = 0; j < 16; ++j) {
                int d  = dc + j;
                int dg = d >> 3;
                int pg = dg ^ ((dg & 1) << 2);
                Vl2[d][(((row >> 3) ^ pg) << 3) + (row & 7)] = o[j];
            }
        }
        __syncthreads();
        {
            const int d  = tid >> 2;
            const int kc = (tid & 3) * 16;
            const int dg = d >> 3;
            const int pg = dg ^ ((dg & 1) << 2);
            uint4 x0 = *(const uint4*)&Vl2[d][(((kc >> 3)    ) ^ pg) << 3];
            uint4 x1 = *(const uint4*)&Vl2[d][(((kc >> 3) + 1) ^ pg) << 3];
            size_t vo = ((size_t)(n * NHEAD + h) * HDIM + d) * L_SEQ + t * 64 + kc;
            *(uint4*)(Vt + vo)     = x0;
            *(uint4*)(Vt + vo + 8) = x1;
        }
    } else if (b < QKV_BLOCKS + WCVT_BLOCKS) {
        int i = ((b - QKV_BLOCKS) * 256 + tid) * 8;
        u16 o[8];
        cvt8(*(const float4*)(Wg + i), *(const float4*)(Wg + i + 4), o, 1.f);
        *(uint4*)(Wb + i) = *(const uint4*)o;
    } else {
        const int row  = b - (QKV_BLOCKS + WCVT_BLOCKS);   // 0..4095
        const int wv   = tid >> 6;
        const int lane = tid & 63;
        const int* mp = Mg + (size_t)row * L_SEQ + lane;
        u64* op = maskp + (size_t)row * (L_SEQ / 64);
        #pragma unroll
        for (int u = 0; u < 8; ++u) {
            int t = wv * 8 + u;
            u64 bits = __ballot(mp[t * 64] != 0);
            if (lane == 0) op[t] = bits;
        }
    }
}

// ---------------------------------------------------------------------------
// Flash attention, fixed-max softmax (p = exp(s-16), exact after final
// normalize). K-tile 64, register prefetch. Pl uses the XOR swizzle:
// element (q,k) at slot ((k>>3) ^ ((q>>2)<<1))*8 + (k&7)  -> conflict-free
// scatter writes AND broadcast-free b128 A-fragment reads.
// ---------------------------------------------------------------------------
__global__ __launch_bounds__(256, 4)
void attn_kernel(const u16* __restrict__ Qb, const u16* __restrict__ Kb,
                 const u16* __restrict__ Vt, const u64* __restrict__ maskp,
                 u16* __restrict__ Og)
{
    const int qblk = blockIdx.x;
    const int h    = blockIdx.y;
    const int n    = blockIdx.z;
    const int tid  = threadIdx.x;
    const int wave = tid >> 6;
    const int lane = tid & 63;
    const int l16  = lane & 15;
    const int quad = lane >> 4;

    __shared__ u16 Kl[64][72];      // [k][d]
    __shared__ u16 Vl[64][72];      // [d][k]
    __shared__ u16 Pl[4][16][64];   // per-wave, swizzled

    const int q0 = qblk * 64 + wave * 16;

    bf16x8 qf[2];
    {
        const u16* qp = Qb + ((size_t)(n * L_SEQ) + q0 + l16) * EMB + h * HDIM;
        qf[0] = *(const bf16x8*)(qp + quad * 8);
        qf[1] = *(const bf16x8*)(qp + 32 + quad * 8);
    }

    f32x4 acc[4];
    #pragma unroll
    for (int c = 0; c < 4; ++c)
        #pragma unroll
        for (int r = 0; r < 4; ++r) acc[c][r] = 0.f;
    float lsum[4] = {0.f, 0.f, 0.f, 0.f};

    const u16* kbase = Kb + (size_t)(n * NHEAD + h) * L_SEQ * HDIM;
    const u16* vbase = Vt + (size_t)(n * NHEAD + h) * HDIM * L_SEQ;
    const u64* mbase = maskp + ((size_t)(n * L_SEQ) + q0 + quad * 4) * (L_SEQ / 64);

    const int srow = tid >> 2;           // 0..63
    const int scol = (tid & 3) * 16;     // 0,16,32,48

    uint4 kr0, kr1, vr0, vr1;
    u64 mr[4];
    {
        const u16* kp = kbase + (size_t)srow * HDIM + scol;
        const u16* vp = vbase + (size_t)srow * L_SEQ + scol;
        kr0 = *(const uint4*)kp;  kr1 = *(const uint4*)(kp + 8);
        vr0 = *(const uint4*)vp;  vr1 = *(const uint4*)(vp + 8);
        #pragma unroll
        for (int r = 0; r < 4; ++r) mr[r] = mbase[(size_t)r * (L_SEQ / 64)];
    }

    for (int t = 0; t < L_SEQ / 64; ++t) {
        __syncthreads();
        *(uint4*)&Kl[srow][scol]     = kr0;
        *(uint4*)&Kl[srow][scol + 8] = kr1;
        *(uint4*)&Vl[srow][scol]     = vr0;
        *(uint4*)&Vl[srow][scol + 8] = vr1;
        u64 mcur[4];
        #pragma unroll
        for (int r = 0; r < 4; ++r) mcur[r] = mr[r];

        if (t + 1 < L_SEQ / 64) {
            const u16* kp = kbase + (size_t)((t + 1) * 64 + srow) * HDIM + scol;
            const u16* vp = vbase + (size_t)srow * L_SEQ + (t + 1) * 64 + scol;
            kr0 = *(const uint4*)kp;  kr1 = *(const uint4*)(kp + 8);
            vr0 = *(const uint4*)vp;  vr1 = *(const uint4*)(vp + 8);
            #pragma unroll
            for (int r = 0; r < 4; ++r) mr[r] = mbase[(size_t)r * (L_SEQ / 64) + t + 1];
        }
        __syncthreads();

        // ---- S = (Q/8) K^T : 16 x 64 ----
        f32x4 S[4];
        #pragma unroll
        for (int cc = 0; cc < 4; ++cc) {
            bf16x8 b0 = *(const bf16x8*)&Kl[cc * 16 + l16][quad * 8];
            bf16x8 b1 = *(const bf16x8*)&Kl[cc * 16 + l16][32 + quad * 8];
            f32x4 z; z[0]=0.f; z[1]=0.f; z[2]=0.f; z[3]=0.f;
            z = __builtin_amdgcn_mfma_f32_16x16x32_bf16(qf[0], b0, z, 0, 0, 0);
            z = __builtin_amdgcn_mfma_f32_16x16x32_bf16(qf[1], b1, z, 0, 0, 0);
            S[cc] = z;
        }

        // ---- p = mask ? exp(s-16) : 0 ; per-lane partial sums ----
        #pragma unroll
        for (int cc = 0; cc < 4; ++cc) {
            #pragma unroll
            for (int r = 0; r < 4; ++r) {
                float s = ((mcur[r] >> (cc * 16 + l16)) & 1ull) ? S[cc][r] : -1.0e20f;
                float p = __expf(s - 16.f);
                S[cc][r] = p;
                lsum[r] += p;
            }
        }

        // ---- P -> swizzled LDS: (q=quad*4+r, k=cc*16+l16) ----
        #pragma unroll
        for (int cc = 0; cc < 2; ++cc) {
            // two 8-groups per cc-chunk: group index k>>3 = cc*2 + (l16>>3)
        }
        #pragma unroll
        for (int cc = 0; cc < 4; ++cc) {
            const int slot = (((cc * 2 + (l16 >> 3)) ^ (quad << 1)) << 3) + (l16 & 7);
            #pragma unroll
            for (int r = 0; r < 4; ++r)
                Pl[wave][quad * 4 + r][slot] = f2bf(S[cc][r]);
        }

        asm volatile("s_waitcnt lgkmcnt(0)" ::: "memory");

        // ---- O += P V ----
        #pragma unroll
        for (int kc = 0; kc < 2; ++kc) {
            bf16x8 pf = *(const bf16x8*)
                &Pl[wave][l16][(((kc * 4 + quad) ^ ((l16 >> 2) << 1)) << 3)];
            #pragma unroll
            for (int dc = 0; dc < 4; ++dc) {
                bf16x8 vf = *(const bf16x8*)&Vl[dc * 16 + l16][kc * 32 + quad * 8];
                acc[dc] = __builtin_amdgcn_mfma_f32_16x16x32_bf16(pf, vf, acc[dc], 0, 0, 0);
            }
        }
    }

    #pragma unroll
    for (int r = 0; r < 4; ++r) {
        float s = lsum[r];
        s += __shfl_xor(s, 1);
        s += __shfl_xor(s, 2);
        s += __shfl_xor(s, 4);
        s += __shfl_xor(s, 8);
        float inv = 1.f / s;
        u16* op = Og + ((size_t)(n * L_SEQ) + q0 + quad * 4 + r) * EMB + h * HDIM;
        #pragma unroll
        for (int dc = 0; dc < 4; ++dc)
            op[dc * 16 + l16] = f2bf(acc[dc][r] * inv);
    }
}

// ---------------------------------------------------------------------------
// out(fp32) = attn(4096x1024 bf16) @ Wb^T + bias.
// 64M x 128N tiles -> 512 blocks (2/CU); 4 waves of 32x64; BK=64, prefetched.
// ---------------------------------------------------------------------------
__global__ __launch_bounds__(256, 4)
void out_gemm(const u16* __restrict__ A, const u16* __restrict__ B,
              const float* __restrict__ bias, float* __restrict__ out)
{
    const int bn  = blockIdx.x;   // 0..7   (N/128)
    const int bm  = blockIdx.y;   // 0..63  (M/64)
    const int tid = threadIdx.x;
    const int wave = tid >> 6;
    const int lane = tid & 63;
    const int l16  = lane & 15;
    const int quad = lane >> 4;
    const int wr = wave >> 1, wc = wave & 1;

    __shared__ u16 Al[64][72];
    __shared__ u16 Bl[128][72];

    f32x4 acc[2][4];
    #pragma unroll
    for (int i = 0; i < 2; ++i)
        #pragma unroll
        for (int j = 0; j < 4; ++j)
            #pragma unroll
            for (int r = 0; r < 4; ++r) acc[i][j][r] = 0.f;

    const int arow = tid >> 2, akc = (tid & 3) * 16;
    const int brow = tid >> 1, bkc = (tid & 1) * 32;

    const u16* ap = A + (size_t)(bm * 64  + arow) * EMB + akc;
    const u16* bp = B + (size_t)(bn * 128 + brow) * EMB + bkc;

    uint4 ar0 = *(const uint4*)ap, ar1 = *(const uint4*)(ap + 8);
    uint4 br[4];
    #pragma unroll
    for (int u = 0; u < 4; ++u) br[u] = *(const uint4*)(bp + u * 8);

    for (int k0 = 0; k0 < EMB; k0 += 64) {
        __syncthreads();
        *(uint4*)&Al[arow][akc]     = ar0;
        *(uint4*)&Al[arow][akc + 8] = ar1;
        #pragma unroll
        for (int u = 0; u < 4; ++u) *(uint4*)&Bl[brow][bkc + u * 8] = br[u];
        if (k0 + 64 < EMB) {
            ar0 = *(const uint4*)(ap + k0 + 64);
            ar1 = *(const uint4*)(ap + k0 + 72);
            #pragma unroll
            for (int u = 0; u < 4; ++u) br[u] = *(const uint4*)(bp + k0 + 64 + u * 8);
        }
        __syncthreads();

        #pragma unroll
        for (int kk = 0; kk < 2; ++kk) {
            bf16x8 af[2], bfr[4];
            #pragma unroll
            for (int i = 0; i < 2; ++i)
                af[i] = *(const bf16x8*)&Al[wr * 32 + i * 16 + l16][kk * 32 + quad * 8];
            #pragma unroll
            for (int j = 0; j < 4; ++j)
                bfr[j] = *(const bf16x8*)&Bl[wc * 64 + j * 16 + l16][kk * 32 + quad * 8];
            #pragma unroll
            for (int i = 0; i < 2; ++i)
                #pragma unroll
                for (int j = 0; j < 4; ++j)
                    acc[i][j] = __builtin_amdgcn_mfma_f32_16x16x32_bf16(af[i], bfr[j], acc[i][j], 0, 0, 0);
        }
    }

    #pragma unroll
    for (int j = 0; j < 4; ++j) {
        int col = bn * 128 + wc * 64 + j * 16 + l16;
        float bv = bias[col];
        #pragma unroll
        for (int i = 0; i < 2; ++i) {
            int row0 = bm * 64 + wr * 32 + i * 16 + quad * 4;
            #pragma unroll
            for (int r = 0; r < 4; ++r)
                out[(size_t)(row0 + r) * EMB + col] = acc[i][j][r] + bv;
        }
    }
}

extern "C" void kernel_launch(void* const* d_in, const int* in_sizes, int n_in,
                              void* d_out, int out_size, void* d_ws, size_t ws_size,
                              hipStream_t stream)
{
    const float* Vg = (const float*)d_in[0];
    const float* Kg = (const float*)d_in[1];
    const float* Qg = (const float*)d_in[2];
    const int*   Mg = (const int*)d_in[3];
    const float* Wg = (const float*)d_in[4];
    const float* Bg = (const float*)d_in[5];
    float* Og = (float*)d_out;

    const size_t QKV = (size_t)NBATCH * L_SEQ * EMB;   // 4M elems
    char* ws = (char*)d_ws;
    u16* attn_ws = (u16*)ws;                                  // 8 MB
    u16* Wb      = (u16*)(ws + QKV * 2);                      // 2 MB
    u16* Qb      = (u16*)(ws + QKV * 2 + 2 * 1024 * 1024);
    u16* Kb      = Qb + QKV;
    u16* Vt      = Kb + QKV;
    u64* maskp   = (u64*)(Vt + QKV);                          // 1 MB

    prep_all<<<dim3(QKV_BLOCKS + WCVT_BLOCKS + NBATCH * L_SEQ), 256, 0, stream>>>(
        Qg, Kg, Vg, Wg, Mg, Qb, Kb, Vt, Wb, maskp);

    dim3 g1(L_SEQ / 64, NHEAD, NBATCH);
    attn_kernel<<<g1, 256, 0, stream>>>(Qb, Kb, Vt, maskp, attn_ws);

    dim3 g2(EMB / 128, (NBATCH * L_SEQ) / 64);
    out_gemm<<<g2, 256, 0, stream>>>(attn_ws, Wb, Bg, Og);
}